// Round 4
// baseline (869.623 us; speedup 1.0000x reference)
//
#include <hip/hip_runtime.h>
#include <hip/hip_bf16.h>

#define DIM 512
#define NUM_HEADS 16
#define HEAD_DIM 32
#define WHALF 128
#define MEMN 16
#define SEQ 2048
#define BATCH 2
#define T_TOT (SEQ + MEMN)   // 2064
#define MAX_KEYS (MEMN + 2*WHALF + 1)  // 273

// ---------------------------------------------------------------------------
// Fused QKV projection: Y[row][col] = dot(xrow, W[:,col]) + b[col]
// xrow = mem[t] for t<MEM else X[b][t-MEM].
// grid: (B*T/8, 2, 3[q,k,v]); block 256. Each block: 8 rows x 256 cols.
// ---------------------------------------------------------------------------
__global__ __launch_bounds__(256) void qkv_proj(
    const float* __restrict__ q_in, const float* __restrict__ k_in,
    const float* __restrict__ v_in, const float* __restrict__ memp,
    const float* __restrict__ Wq, const float* __restrict__ bq,
    const float* __restrict__ Wk, const float* __restrict__ bk,
    const float* __restrict__ Wv, const float* __restrict__ bv,
    float* __restrict__ Qo, float* __restrict__ Ko, float* __restrict__ Vo)
{
    const int which = blockIdx.z;
    const float* X    = which == 0 ? q_in : (which == 1 ? k_in : v_in);
    const float* W    = which == 0 ? Wq   : (which == 1 ? Wk   : Wv);
    const float* bias = which == 0 ? bq   : (which == 1 ? bk   : bv);
    float*       Y    = which == 0 ? Qo   : (which == 1 ? Ko   : Vo);

    const int col  = blockIdx.y * 256 + threadIdx.x;
    const int row0 = blockIdx.x * 8;

    __shared__ float4 s_x4[8][DIM / 4];   // 16 KiB

    // stage 8 input rows (coalesced float4)
    for (int idx = threadIdx.x; idx < 8 * (DIM / 4); idx += 256) {
        int r  = idx >> 7;          // /128
        int kk = idx & 127;
        int row = row0 + r;
        int b = row / T_TOT;
        int t = row - b * T_TOT;
        const float4* src = (t < MEMN)
            ? (const float4*)(memp + (size_t)t * DIM)
            : (const float4*)(X + ((size_t)b * SEQ + (t - MEMN)) * DIM);
        s_x4[r][kk] = src[kk];
    }
    __syncthreads();

    float acc[8];
    const float bb = bias[col];
    #pragma unroll
    for (int r = 0; r < 8; ++r) acc[r] = bb;

    for (int k4 = 0; k4 < DIM / 4; ++k4) {
        const int k = k4 * 4;
        const float w0 = W[(size_t)(k + 0) * DIM + col];
        const float w1 = W[(size_t)(k + 1) * DIM + col];
        const float w2 = W[(size_t)(k + 2) * DIM + col];
        const float w3 = W[(size_t)(k + 3) * DIM + col];
        #pragma unroll
        for (int r = 0; r < 8; ++r) {
            const float4 x = s_x4[r][k4];
            acc[r] = fmaf(x.x, w0, acc[r]);
            acc[r] = fmaf(x.y, w1, acc[r]);
            acc[r] = fmaf(x.z, w2, acc[r]);
            acc[r] = fmaf(x.w, w3, acc[r]);
        }
    }

    #pragma unroll
    for (int r = 0; r < 8; ++r)
        Y[(size_t)(row0 + r) * DIM + col] = acc[r];
}

// ---------------------------------------------------------------------------
// Windowed attention with memory tokens. One wave per (query i, head h, b).
// keys = [0,16) ∪ [max(16,i-128), min(T-1,i+128)]
// ---------------------------------------------------------------------------
__global__ __launch_bounds__(64) void attn_kernel(
    const float* __restrict__ Q, const float* __restrict__ K,
    const float* __restrict__ V, float* __restrict__ ctx)
{
    const int i    = MEMN + blockIdx.x;   // query index in [16, T)
    const int h    = blockIdx.y;
    const int b    = blockIdx.z;
    const int lane = threadIdx.x;

    __shared__ float s_q[HEAD_DIM];
    __shared__ float s_sc[MAX_KEYS];

    const float scale = 0.17677669529663687f;   // 1/sqrt(32)

    const float* qrow = Q + ((size_t)(b * T_TOT + i) * DIM + h * HEAD_DIM);
    if (lane < HEAD_DIM) s_q[lane] = qrow[lane];
    __syncthreads();

    int lo = i - WHALF; if (lo < MEMN) lo = MEMN;
    int hi = i + WHALF; if (hi > T_TOT - 1) hi = T_TOT - 1;
    const int nw = hi - lo + 1;
    const int total = MEMN + nw;

    for (int jj = lane; jj < total; jj += 64) {
        const int j = (jj < MEMN) ? jj : lo + (jj - MEMN);
        const float* krow = K + ((size_t)(b * T_TOT + j) * DIM + h * HEAD_DIM);
        float d = 0.f;
        #pragma unroll
        for (int t4 = 0; t4 < HEAD_DIM / 4; ++t4) {
            const float4 kv = ((const float4*)krow)[t4];
            d = fmaf(s_q[t4 * 4 + 0], kv.x, d);
            d = fmaf(s_q[t4 * 4 + 1], kv.y, d);
            d = fmaf(s_q[t4 * 4 + 2], kv.z, d);
            d = fmaf(s_q[t4 * 4 + 3], kv.w, d);
        }
        s_sc[jj] = d * scale;
    }
    __syncthreads();

    // wave max
    float m = -1e30f;
    for (int jj = lane; jj < total; jj += 64) m = fmaxf(m, s_sc[jj]);
    #pragma unroll
    for (int off = 32; off; off >>= 1) m = fmaxf(m, __shfl_xor(m, off));

    // exp + wave sum
    float ssum = 0.f;
    for (int jj = lane; jj < total; jj += 64) {
        const float e = __expf(s_sc[jj] - m);
        s_sc[jj] = e;
        ssum += e;
    }
    #pragma unroll
    for (int off = 32; off; off >>= 1) ssum += __shfl_xor(ssum, off);
    __syncthreads();

    const float inv = 1.0f / ssum;
    const int d    = lane & 31;
    const int half = lane >> 5;
    float acc = 0.f;
    for (int jj = half; jj < total; jj += 2) {
        const int j = (jj < MEMN) ? jj : lo + (jj - MEMN);
        acc = fmaf(s_sc[jj], V[(size_t)(b * T_TOT + j) * DIM + h * HEAD_DIM + d], acc);
    }
    acc += __shfl_down(acc, 32);
    if (lane < 32)
        ctx[((size_t)b * SEQ + (i - MEMN)) * DIM + h * HEAD_DIM + d] = acc * inv;
}

// ---------------------------------------------------------------------------
// Output projection: out = ctx @ Wo + bo   (rows = B*S)
// ---------------------------------------------------------------------------
__global__ __launch_bounds__(256) void out_proj(
    const float* __restrict__ ctx, const float* __restrict__ Wo,
    const float* __restrict__ bo, float* __restrict__ out)
{
    const int col  = blockIdx.y * 256 + threadIdx.x;
    const int row0 = blockIdx.x * 8;

    __shared__ float4 s_x4[8][DIM / 4];

    for (int idx = threadIdx.x; idx < 8 * (DIM / 4); idx += 256) {
        int r  = idx >> 7;
        int kk = idx & 127;
        s_x4[r][kk] = ((const float4*)(ctx + (size_t)(row0 + r) * DIM))[kk];
    }
    __syncthreads();

    float acc[8];
    const float bb = bo[col];
    #pragma unroll
    for (int r = 0; r < 8; ++r) acc[r] = bb;

    for (int k4 = 0; k4 < DIM / 4; ++k4) {
        const int k = k4 * 4;
        const float w0 = Wo[(size_t)(k + 0) * DIM + col];
        const float w1 = Wo[(size_t)(k + 1) * DIM + col];
        const float w2 = Wo[(size_t)(k + 2) * DIM + col];
        const float w3 = Wo[(size_t)(k + 3) * DIM + col];
        #pragma unroll
        for (int r = 0; r < 8; ++r) {
            const float4 x = s_x4[r][k4];
            acc[r] = fmaf(x.x, w0, acc[r]);
            acc[r] = fmaf(x.y, w1, acc[r]);
            acc[r] = fmaf(x.z, w2, acc[r]);
            acc[r] = fmaf(x.w, w3, acc[r]);
        }
    }

    #pragma unroll
    for (int r = 0; r < 8; ++r)
        out[(size_t)(row0 + r) * DIM + col] = acc[r];
}

// ---------------------------------------------------------------------------
extern "C" void kernel_launch(void* const* d_in, const int* in_sizes, int n_in,
                              void* d_out, int out_size, void* d_ws, size_t ws_size,
                              hipStream_t stream) {
    const float* q    = (const float*)d_in[0];
    const float* k    = (const float*)d_in[1];
    const float* v    = (const float*)d_in[2];
    const float* memp = (const float*)d_in[3];
    const float* Wq   = (const float*)d_in[4];
    const float* bq   = (const float*)d_in[5];
    const float* Wk   = (const float*)d_in[6];
    const float* bk   = (const float*)d_in[7];
    const float* Wv   = (const float*)d_in[8];
    const float* bv   = (const float*)d_in[9];
    const float* Wo   = (const float*)d_in[10];
    const float* bo   = (const float*)d_in[11];
    float* out = (float*)d_out;

    const size_t projN = (size_t)BATCH * T_TOT * DIM;   // 2,113,536 floats
    float* Qb = (float*)d_ws;
    float* Kb = Qb + projN;
    float* Vb = Kb + projN;
    float* Cb = Vb + projN;                             // B*S*D floats

    dim3 g1(BATCH * T_TOT / 8, 2, 3);
    qkv_proj<<<g1, 256, 0, stream>>>(q, k, v, memp, Wq, bq, Wk, bk, Wv, bv,
                                     Qb, Kb, Vb);

    dim3 g2(SEQ, NUM_HEADS, BATCH);
    attn_kernel<<<g2, 64, 0, stream>>>(Qb, Kb, Vb, Cb);

    dim3 g3(BATCH * SEQ / 8, 2, 1);
    out_proj<<<g3, 256, 0, stream>>>(Cb, Wo, bo, out);
}

// Round 5
// 313.612 us; speedup vs baseline: 2.7729x; 2.7729x over previous
//
#include <hip/hip_runtime.h>
#include <hip/hip_bf16.h>

#define DIM 512
#define NUM_HEADS 16
#define HEAD_DIM 32
#define WHALF 128
#define MEMN 16
#define SEQ 2048
#define BATCH 2
#define T_TOT (SEQ + MEMN)   // 2064
#define QBLK 64
#define MAXK (MEMN + QBLK + 2*WHALF + 1)   // 337

// ---------------------------------------------------------------------------
// Fused QKV projection (unchanged from baseline)
// ---------------------------------------------------------------------------
__global__ __launch_bounds__(256) void qkv_proj(
    const float* __restrict__ q_in, const float* __restrict__ k_in,
    const float* __restrict__ v_in, const float* __restrict__ memp,
    const float* __restrict__ Wq, const float* __restrict__ bq,
    const float* __restrict__ Wk, const float* __restrict__ bk,
    const float* __restrict__ Wv, const float* __restrict__ bv,
    float* __restrict__ Qo, float* __restrict__ Ko, float* __restrict__ Vo)
{
    const int which = blockIdx.z;
    const float* X    = which == 0 ? q_in : (which == 1 ? k_in : v_in);
    const float* W    = which == 0 ? Wq   : (which == 1 ? Wk   : Wv);
    const float* bias = which == 0 ? bq   : (which == 1 ? bk   : bv);
    float*       Y    = which == 0 ? Qo   : (which == 1 ? Ko   : Vo);

    const int col  = blockIdx.y * 256 + threadIdx.x;
    const int row0 = blockIdx.x * 8;

    __shared__ float4 s_x4[8][DIM / 4];   // 16 KiB

    for (int idx = threadIdx.x; idx < 8 * (DIM / 4); idx += 256) {
        int r  = idx >> 7;
        int kk = idx & 127;
        int row = row0 + r;
        int b = row / T_TOT;
        int t = row - b * T_TOT;
        const float4* src = (t < MEMN)
            ? (const float4*)(memp + (size_t)t * DIM)
            : (const float4*)(X + ((size_t)b * SEQ + (t - MEMN)) * DIM);
        s_x4[r][kk] = src[kk];
    }
    __syncthreads();

    float acc[8];
    const float bb = bias[col];
    #pragma unroll
    for (int r = 0; r < 8; ++r) acc[r] = bb;

    for (int k4 = 0; k4 < DIM / 4; ++k4) {
        const int k = k4 * 4;
        const float w0 = W[(size_t)(k + 0) * DIM + col];
        const float w1 = W[(size_t)(k + 1) * DIM + col];
        const float w2 = W[(size_t)(k + 2) * DIM + col];
        const float w3 = W[(size_t)(k + 3) * DIM + col];
        #pragma unroll
        for (int r = 0; r < 8; ++r) {
            const float4 x = s_x4[r][k4];
            acc[r] = fmaf(x.x, w0, acc[r]);
            acc[r] = fmaf(x.y, w1, acc[r]);
            acc[r] = fmaf(x.z, w2, acc[r]);
            acc[r] = fmaf(x.w, w3, acc[r]);
        }
    }

    #pragma unroll
    for (int r = 0; r < 8; ++r)
        Y[(size_t)(row0 + r) * DIM + col] = acc[r];
}

// ---------------------------------------------------------------------------
// Tiled windowed attention. Block = 256 threads = 4 waves x 16 queries.
// K/V union window staged once into LDS as bf16, shared by 64 queries.
// Per query: 4 lanes, 8 d-elements each; fp32 online softmax.
// ---------------------------------------------------------------------------
__global__ __launch_bounds__(256) void attn_tiled(
    const float* __restrict__ Q, const float* __restrict__ K,
    const float* __restrict__ V, float* __restrict__ ctx)
{
    const int tid  = threadIdx.x;
    const int tile = blockIdx.x;          // 0..SEQ/QBLK-1
    const int h    = blockIdx.y;
    const int b    = blockIdx.z;
    const int wave = tid >> 6;            // 0..3
    const int lane = tid & 63;
    const int ql   = lane >> 2;           // 0..15  query within wave
    const int sub  = lane & 3;            // 0..3   d-slice (8 floats)

    const int i0 = MEMN + tile * QBLK;    // first query t-index of block
    int klo = i0 - WHALF;            if (klo < MEMN)      klo = MEMN;
    int khi = i0 + QBLK - 1 + WHALF; if (khi > T_TOT - 1) khi = T_TOT - 1;
    const int total = MEMN + (khi - klo + 1);   // <= MAXK

    __shared__ __hip_bfloat16 sK[MAXK][HEAD_DIM];   // 21.1 KiB
    __shared__ __hip_bfloat16 sV[MAXK][HEAD_DIM];   // 21.1 KiB

    const size_t bhbase = (size_t)b * T_TOT * DIM + (size_t)h * HEAD_DIM;

    // ---- stage K,V window (coalesced: 8 threads x float4 per row) ----
    for (int idx = tid; idx < total * 8; idx += 256) {
        const int r = idx >> 3;
        const int c = idx & 7;
        const int g = (r < MEMN) ? r : (klo + r - MEMN);
        const size_t goff = bhbase + (size_t)g * DIM + c * 4;
        const float4 k4 = *(const float4*)(K + goff);
        const float4 v4 = *(const float4*)(V + goff);
        union { __hip_bfloat16 hh[4]; uint2 u; } pk, pv;
        pk.hh[0] = __float2bfloat16(k4.x); pk.hh[1] = __float2bfloat16(k4.y);
        pk.hh[2] = __float2bfloat16(k4.z); pk.hh[3] = __float2bfloat16(k4.w);
        pv.hh[0] = __float2bfloat16(v4.x); pv.hh[1] = __float2bfloat16(v4.y);
        pv.hh[2] = __float2bfloat16(v4.z); pv.hh[3] = __float2bfloat16(v4.w);
        *(uint2*)&sK[r][c * 4] = pk.u;
        *(uint2*)&sV[r][c * 4] = pv.u;
    }

    // ---- Q slice into registers, pre-scaled by 1/sqrt(HEAD_DIM) ----
    const int iq = i0 + wave * 16 + ql;   // this lane's query (t-index)
    const float scale = 0.17677669529663687f;
    float qr[8];
    {
        const float* qp = Q + bhbase + (size_t)iq * DIM + sub * 8;
        const float4 a  = *(const float4*)qp;
        const float4 c4 = *(const float4*)(qp + 4);
        qr[0] = a.x  * scale; qr[1] = a.y  * scale;
        qr[2] = a.z  * scale; qr[3] = a.w  * scale;
        qr[4] = c4.x * scale; qr[5] = c4.y * scale;
        qr[6] = c4.z * scale; qr[7] = c4.w * scale;
    }

    __syncthreads();

    float m = -1e30f, l = 0.f;
    float o0 = 0.f, o1 = 0.f, o2 = 0.f, o3 = 0.f,
          o4 = 0.f, o5 = 0.f, o6 = 0.f, o7 = 0.f;

    const int iw0 = i0 + wave * 16;       // wave's first query
    int wlo = iw0 - WHALF;      if (wlo < MEMN)      wlo = MEMN;
    int whi = iw0 + 15 + WHALF; if (whi > T_TOT - 1) whi = T_TOT - 1;
    const int jlo = iq - WHALF;           // per-query valid key range
    const int jhi = iq + WHALF;

    auto process = [&](int idx, bool valid) {
        const uint4 ku = *(const uint4*)&sK[idx][sub * 8];
        float d0 = 0.f, d1 = 0.f;
        uint32_t u;
        u = ku.x;
        d0 = fmaf(qr[0], __uint_as_float(u << 16), d0);
        d1 = fmaf(qr[1], __uint_as_float(u & 0xffff0000u), d1);
        u = ku.y;
        d0 = fmaf(qr[2], __uint_as_float(u << 16), d0);
        d1 = fmaf(qr[3], __uint_as_float(u & 0xffff0000u), d1);
        u = ku.z;
        d0 = fmaf(qr[4], __uint_as_float(u << 16), d0);
        d1 = fmaf(qr[5], __uint_as_float(u & 0xffff0000u), d1);
        u = ku.w;
        d0 = fmaf(qr[6], __uint_as_float(u << 16), d0);
        d1 = fmaf(qr[7], __uint_as_float(u & 0xffff0000u), d1);
        float s = d0 + d1;
        s += __shfl_xor(s, 1);
        s += __shfl_xor(s, 2);
        if (!valid) s = -1e30f;
        const float mn    = fmaxf(m, s);
        const float alpha = __expf(m - mn);
        const float p     = __expf(s - mn);
        l = l * alpha + p;
        m = mn;
        const uint4 vu = *(const uint4*)&sV[idx][sub * 8];
        float pv;
        u = vu.x;
        pv = p * __uint_as_float(u << 16);          o0 = fmaf(o0, alpha, pv);
        pv = p * __uint_as_float(u & 0xffff0000u);  o1 = fmaf(o1, alpha, pv);
        u = vu.y;
        pv = p * __uint_as_float(u << 16);          o2 = fmaf(o2, alpha, pv);
        pv = p * __uint_as_float(u & 0xffff0000u);  o3 = fmaf(o3, alpha, pv);
        u = vu.z;
        pv = p * __uint_as_float(u << 16);          o4 = fmaf(o4, alpha, pv);
        pv = p * __uint_as_float(u & 0xffff0000u);  o5 = fmaf(o5, alpha, pv);
        u = vu.w;
        pv = p * __uint_as_float(u << 16);          o6 = fmaf(o6, alpha, pv);
        pv = p * __uint_as_float(u & 0xffff0000u);  o7 = fmaf(o7, alpha, pv);
    };

    // memory keys: always valid for every query
    #pragma unroll 4
    for (int jj = 0; jj < MEMN; ++jj) process(jj, true);
    // wave's window keys, per-query masked
    for (int j = wlo; j <= whi; ++j)
        process(MEMN + (j - klo), (j >= jlo) && (j <= jhi));

    const float inv = 1.0f / l;
    float4 r0, r1;
    r0.x = o0 * inv; r0.y = o1 * inv; r0.z = o2 * inv; r0.w = o3 * inv;
    r1.x = o4 * inv; r1.y = o5 * inv; r1.z = o6 * inv; r1.w = o7 * inv;
    float* op = ctx + ((size_t)b * SEQ + (iq - MEMN)) * DIM
                    + (size_t)h * HEAD_DIM + sub * 8;
    *(float4*)op       = r0;
    *(float4*)(op + 4) = r1;
}

// ---------------------------------------------------------------------------
// Output projection (unchanged from baseline)
// ---------------------------------------------------------------------------
__global__ __launch_bounds__(256) void out_proj(
    const float* __restrict__ ctx, const float* __restrict__ Wo,
    const float* __restrict__ bo, float* __restrict__ out)
{
    const int col  = blockIdx.y * 256 + threadIdx.x;
    const int row0 = blockIdx.x * 8;

    __shared__ float4 s_x4[8][DIM / 4];

    for (int idx = threadIdx.x; idx < 8 * (DIM / 4); idx += 256) {
        int r  = idx >> 7;
        int kk = idx & 127;
        s_x4[r][kk] = ((const float4*)(ctx + (size_t)(row0 + r) * DIM))[kk];
    }
    __syncthreads();

    float acc[8];
    const float bb = bo[col];
    #pragma unroll
    for (int r = 0; r < 8; ++r) acc[r] = bb;

    for (int k4 = 0; k4 < DIM / 4; ++k4) {
        const int k = k4 * 4;
        const float w0 = Wo[(size_t)(k + 0) * DIM + col];
        const float w1 = Wo[(size_t)(k + 1) * DIM + col];
        const float w2 = Wo[(size_t)(k + 2) * DIM + col];
        const float w3 = Wo[(size_t)(k + 3) * DIM + col];
        #pragma unroll
        for (int r = 0; r < 8; ++r) {
            const float4 x = s_x4[r][k4];
            acc[r] = fmaf(x.x, w0, acc[r]);
            acc[r] = fmaf(x.y, w1, acc[r]);
            acc[r] = fmaf(x.z, w2, acc[r]);
            acc[r] = fmaf(x.w, w3, acc[r]);
        }
    }

    #pragma unroll
    for (int r = 0; r < 8; ++r)
        out[(size_t)(row0 + r) * DIM + col] = acc[r];
}

// ---------------------------------------------------------------------------
extern "C" void kernel_launch(void* const* d_in, const int* in_sizes, int n_in,
                              void* d_out, int out_size, void* d_ws, size_t ws_size,
                              hipStream_t stream) {
    const float* q    = (const float*)d_in[0];
    const float* k    = (const float*)d_in[1];
    const float* v    = (const float*)d_in[2];
    const float* memp = (const float*)d_in[3];
    const float* Wq   = (const float*)d_in[4];
    const float* bq   = (const float*)d_in[5];
    const float* Wk   = (const float*)d_in[6];
    const float* bk   = (const float*)d_in[7];
    const float* Wv   = (const float*)d_in[8];
    const float* bv   = (const float*)d_in[9];
    const float* Wo   = (const float*)d_in[10];
    const float* bo   = (const float*)d_in[11];
    float* out = (float*)d_out;

    const size_t projN = (size_t)BATCH * T_TOT * DIM;
    float* Qb = (float*)d_ws;
    float* Kb = Qb + projN;
    float* Vb = Kb + projN;
    float* Cb = Vb + projN;

    dim3 g1(BATCH * T_TOT / 8, 2, 3);
    qkv_proj<<<g1, 256, 0, stream>>>(q, k, v, memp, Wq, bq, Wk, bk, Wv, bv,
                                     Qb, Kb, Vb);

    dim3 g2(SEQ / QBLK, NUM_HEADS, BATCH);
    attn_tiled<<<g2, 256, 0, stream>>>(Qb, Kb, Vb, Cb);

    dim3 g3(BATCH * SEQ / 8, 2, 1);
    out_proj<<<g3, 256, 0, stream>>>(Cb, Wo, bo, out);
}

// Round 6
// 166.592 us; speedup vs baseline: 5.2201x; 1.8825x over previous
//
#include <hip/hip_runtime.h>
#include <hip/hip_bf16.h>
#include <hip/hip_fp16.h>

#define DIM 512
#define NUM_HEADS 16
#define HEAD_DIM 32
#define WHALF 128
#define MEMN 16
#define SEQ 2048
#define BATCH 2
#define T_TOT (SEQ + MEMN)                 // 2064
#define MROWS (BATCH * T_TOT)              // 4128
#define OROWS (BATCH * SEQ)                // 4096
#define QBLK 64
#define MAXK (MEMN + QBLK + 2*WHALF + 1)   // 337

typedef _Float16 f16x8 __attribute__((ext_vector_type(8)));
typedef _Float16 f16x2 __attribute__((ext_vector_type(2)));
typedef float    f32x4 __attribute__((ext_vector_type(4)));

// ---------------------------------------------------------------------------
// Prep 1: build fp16 X matrices [MROWS x 512] for q,k,v (mem rows prepended)
// ---------------------------------------------------------------------------
__global__ __launch_bounds__(256) void cvt_x(
    const float* __restrict__ q, const float* __restrict__ k,
    const float* __restrict__ v, const float* __restrict__ memp,
    ushort* __restrict__ Xq, ushort* __restrict__ Xk, ushort* __restrict__ Xv)
{
    const int which = blockIdx.z;
    const float* X = which == 0 ? q : (which == 1 ? k : v);
    ushort*     Xc = which == 0 ? Xq : (which == 1 ? Xk : Xv);

    const int gid  = blockIdx.x * 256 + threadIdx.x;
    const int base = gid * 8;                     // element offset
    if (base >= MROWS * DIM) return;
    const int row = base >> 9;
    const int c   = base & 511;
    const int b   = row / T_TOT;
    const int t   = row - b * T_TOT;
    const float* src = (t < MEMN)
        ? (memp + (size_t)t * DIM + c)
        : (X + ((size_t)b * SEQ + (t - MEMN)) * DIM + c);
    const float4 a0 = *(const float4*)src;
    const float4 a1 = *(const float4*)(src + 4);
    union { ushort us[8]; uint4 u4; } o;
    _Float16 h;
    h = (_Float16)a0.x; o.us[0] = *(ushort*)&h;
    h = (_Float16)a0.y; o.us[1] = *(ushort*)&h;
    h = (_Float16)a0.z; o.us[2] = *(ushort*)&h;
    h = (_Float16)a0.w; o.us[3] = *(ushort*)&h;
    h = (_Float16)a1.x; o.us[4] = *(ushort*)&h;
    h = (_Float16)a1.y; o.us[5] = *(ushort*)&h;
    h = (_Float16)a1.z; o.us[6] = *(ushort*)&h;
    h = (_Float16)a1.w; o.us[7] = *(ushort*)&h;
    *(uint4*)(Xc + (size_t)row * DIM + c) = o.u4;
}

// ---------------------------------------------------------------------------
// Prep 2: Wt[n][k] = (fp16) W[k][n]  for the 4 weight matrices
// ---------------------------------------------------------------------------
__global__ __launch_bounds__(256) void cvt_wt(
    const float* __restrict__ Wq, const float* __restrict__ Wk,
    const float* __restrict__ Wv, const float* __restrict__ Wo,
    ushort* __restrict__ Wtq, ushort* __restrict__ Wtk,
    ushort* __restrict__ Wtv, ushort* __restrict__ Wto)
{
    const int w = blockIdx.z;
    const float* W  = w == 0 ? Wq  : (w == 1 ? Wk  : (w == 2 ? Wv  : Wo));
    ushort*     Wt  = w == 0 ? Wtq : (w == 1 ? Wtk : (w == 2 ? Wtv : Wto));

    __shared__ float sT[64][65];
    const int n0 = blockIdx.x * 64;
    const int k0 = blockIdx.y * 64;

    for (int e = threadIdx.x; e < 1024; e += 256) {
        const int r  = e >> 4;
        const int c4 = e & 15;
        const float4 f = *(const float4*)(W + (size_t)(k0 + r) * DIM + n0 + c4 * 4);
        sT[r][c4 * 4 + 0] = f.x;
        sT[r][c4 * 4 + 1] = f.y;
        sT[r][c4 * 4 + 2] = f.z;
        sT[r][c4 * 4 + 3] = f.w;
    }
    __syncthreads();
    for (int u = threadIdx.x; u < 512; u += 256) {
        const int n  = u >> 3;
        const int kg = u & 7;
        union { ushort us[8]; uint4 u4; } o;
        #pragma unroll
        for (int j = 0; j < 8; ++j) {
            _Float16 h = (_Float16)sT[kg * 8 + j][n];
            o.us[j] = *(ushort*)&h;
        }
        *(uint4*)(Wt + (size_t)(n0 + n) * DIM + k0 + kg * 8) = o.u4;
    }
}

// ---------------------------------------------------------------------------
// fp16 MFMA GEMM: C[M][512] = A[M][512] @ Wt^T + bias   (Wt is [512 n][512 k])
// 128x128 tile, BK=64, 4 waves; wave -> 64x64 via 4x4 frags of 16x16x32.
// ---------------------------------------------------------------------------
template<bool OUT_HALF>
__device__ __forceinline__ void gemm_body(
    const ushort* __restrict__ A, const ushort* __restrict__ Bt,
    const float* __restrict__ bias, void* __restrict__ C, int M)
{
    __shared__ _Float16 sA[128][72];   // 72 = 64 + 8 pad (16B-aligned rows)
    __shared__ _Float16 sB[128][72];

    const int tid  = threadIdx.x;
    const int row0 = blockIdx.x * 128;
    const int col0 = blockIdx.y * 128;
    const int wave = tid >> 6, lane = tid & 63;
    const int wr = wave >> 1, wc = wave & 1;
    const int fr = lane & 15, fq = lane >> 4;

    f32x4 acc[4][4];
    #pragma unroll
    for (int n = 0; n < 4; ++n) {
        const float bb = bias[col0 + wc * 64 + n * 16 + fr];
        #pragma unroll
        for (int m = 0; m < 4; ++m) acc[m][n] = (f32x4){bb, bb, bb, bb};
    }

    for (int k0 = 0; k0 < 512; k0 += 64) {
        __syncthreads();
        #pragma unroll
        for (int it = 0; it < 8; ++it) {
            const int u  = tid + it * 256;        // [0,2048): A then B units
            const int r  = (u >> 3) & 127;
            const int cc = u & 7;
            if (u < 1024) {
                int gr = row0 + r; if (gr >= M) gr = M - 1;
                *(uint4*)&sA[r][cc * 8] =
                    *(const uint4*)(A + (size_t)gr * 512 + k0 + cc * 8);
            } else {
                *(uint4*)&sB[r][cc * 8] =
                    *(const uint4*)(Bt + (size_t)(col0 + r) * 512 + k0 + cc * 8);
            }
        }
        __syncthreads();
        #pragma unroll
        for (int kk = 0; kk < 2; ++kk) {
            f16x8 a[4], b[4];
            #pragma unroll
            for (int m = 0; m < 4; ++m)
                a[m] = *(const f16x8*)&sA[wr * 64 + m * 16 + fr][kk * 32 + fq * 8];
            #pragma unroll
            for (int n = 0; n < 4; ++n)
                b[n] = *(const f16x8*)&sB[wc * 64 + n * 16 + fr][kk * 32 + fq * 8];
            #pragma unroll
            for (int m = 0; m < 4; ++m)
                #pragma unroll
                for (int n = 0; n < 4; ++n)
                    acc[m][n] = __builtin_amdgcn_mfma_f32_16x16x32_f16(
                        a[m], b[n], acc[m][n], 0, 0, 0);
        }
    }

    #pragma unroll
    for (int m = 0; m < 4; ++m)
        #pragma unroll
        for (int n = 0; n < 4; ++n)
            #pragma unroll
            for (int j = 0; j < 4; ++j) {
                const int row = row0 + wr * 64 + m * 16 + fq * 4 + j;
                const int col = col0 + wc * 64 + n * 16 + fr;
                if (row < M) {
                    if (OUT_HALF) {
                        _Float16 h = (_Float16)acc[m][n][j];
                        ((ushort*)C)[(size_t)row * 512 + col] = *(ushort*)&h;
                    } else {
                        ((float*)C)[(size_t)row * 512 + col] = acc[m][n][j];
                    }
                }
            }
}

__global__ __launch_bounds__(256) void gemm_qkv(
    const ushort* __restrict__ Xq, const ushort* __restrict__ Xk,
    const ushort* __restrict__ Xv,
    const ushort* __restrict__ Wtq, const ushort* __restrict__ Wtk,
    const ushort* __restrict__ Wtv,
    const float* __restrict__ bq, const float* __restrict__ bk,
    const float* __restrict__ bv,
    ushort* __restrict__ Qc, ushort* __restrict__ Kc, ushort* __restrict__ Vc)
{
    const int w = blockIdx.z;
    const ushort* A  = w == 0 ? Xq  : (w == 1 ? Xk  : Xv);
    const ushort* Bt = w == 0 ? Wtq : (w == 1 ? Wtk : Wtv);
    const float*  bi = w == 0 ? bq  : (w == 1 ? bk  : bv);
    ushort*       Cc = w == 0 ? Qc  : (w == 1 ? Kc  : Vc);
    gemm_body<true>(A, Bt, bi, Cc, MROWS);
}

__global__ __launch_bounds__(256) void gemm_out(
    const ushort* __restrict__ A, const ushort* __restrict__ Bt,
    const float* __restrict__ bias, float* __restrict__ C)
{
    gemm_body<false>(A, Bt, bias, C, OROWS);
}

// ---------------------------------------------------------------------------
// Tiled windowed attention (fp16 in/out). Block = 4 waves x 16 queries.
// ---------------------------------------------------------------------------
__global__ __launch_bounds__(256) void attn_tiled(
    const ushort* __restrict__ Q, const ushort* __restrict__ K,
    const ushort* __restrict__ V, ushort* __restrict__ ctx)
{
    const int tid  = threadIdx.x;
    const int tile = blockIdx.x;
    const int h    = blockIdx.y;
    const int b    = blockIdx.z;
    const int wave = tid >> 6;
    const int lane = tid & 63;
    const int ql   = lane >> 2;
    const int sub  = lane & 3;

    const int i0 = MEMN + tile * QBLK;
    int klo = i0 - WHALF;            if (klo < MEMN)      klo = MEMN;
    int khi = i0 + QBLK - 1 + WHALF; if (khi > T_TOT - 1) khi = T_TOT - 1;
    const int total = MEMN + (khi - klo + 1);

    __shared__ ushort sK[MAXK][HEAD_DIM];
    __shared__ ushort sV[MAXK][HEAD_DIM];

    const size_t bhbase = (size_t)b * T_TOT * DIM + (size_t)h * HEAD_DIM;

    // stage K,V window: raw 16B copies (4 lanes per 64B row)
    for (int idx = tid; idx < total * 4; idx += 256) {
        const int r = idx >> 2;
        const int c = idx & 3;
        const int g = (r < MEMN) ? r : (klo + r - MEMN);
        const size_t go = bhbase + (size_t)g * DIM + c * 8;
        *(uint4*)&sK[r][c * 8] = *(const uint4*)(K + go);
        *(uint4*)&sV[r][c * 8] = *(const uint4*)(V + go);
    }

    const int iq = i0 + wave * 16 + ql;
    const float scale = 0.17677669529663687f;
    f16x2 qh[4];
    {
        union { uint4 u; f16x2 h2[4]; } qu;
        qu.u = *(const uint4*)(Q + bhbase + (size_t)iq * DIM + sub * 8);
        #pragma unroll
        for (int j = 0; j < 4; ++j) {
            qh[j][0] = (_Float16)((float)qu.h2[j][0] * scale);
            qh[j][1] = (_Float16)((float)qu.h2[j][1] * scale);
        }
    }

    __syncthreads();

    float m = -1e30f, l = 0.f;
    float o[8];
    #pragma unroll
    for (int j = 0; j < 8; ++j) o[j] = 0.f;

    const int iw0 = i0 + wave * 16;
    int wlo = iw0 - WHALF;      if (wlo < MEMN)      wlo = MEMN;
    int whi = iw0 + 15 + WHALF; if (whi > T_TOT - 1) whi = T_TOT - 1;
    const int jlo = iq - WHALF;
    const int jhi = iq + WHALF;

    auto process = [&](int idx, bool valid) {
        union { uint4 u; f16x2 h2[4]; } ku;
        ku.u = *(const uint4*)&sK[idx][sub * 8];
        float s = 0.f;
#if defined(__has_builtin) && __has_builtin(__builtin_amdgcn_fdot2)
        s = __builtin_amdgcn_fdot2(qh[0], ku.h2[0], s, false);
        s = __builtin_amdgcn_fdot2(qh[1], ku.h2[1], s, false);
        s = __builtin_amdgcn_fdot2(qh[2], ku.h2[2], s, false);
        s = __builtin_amdgcn_fdot2(qh[3], ku.h2[3], s, false);
#else
        #pragma unroll
        for (int j = 0; j < 4; ++j) {
            s = fmaf((float)qh[j][0], (float)ku.h2[j][0], s);
            s = fmaf((float)qh[j][1], (float)ku.h2[j][1], s);
        }
#endif
        s += __shfl_xor(s, 1);
        s += __shfl_xor(s, 2);
        if (!valid) s = -1e30f;
        const float mn    = fmaxf(m, s);
        const float alpha = __expf(m - mn);
        const float p     = __expf(s - mn);
        l = l * alpha + p;
        m = mn;
        union { uint4 u; f16x2 h2[4]; } vu;
        vu.u = *(const uint4*)&sV[idx][sub * 8];
        #pragma unroll
        for (int j = 0; j < 4; ++j) {
            o[2*j]   = fmaf(o[2*j],   alpha, p * (float)vu.h2[j][0]);
            o[2*j+1] = fmaf(o[2*j+1], alpha, p * (float)vu.h2[j][1]);
        }
    };

    #pragma unroll 4
    for (int jj = 0; jj < MEMN; ++jj) process(jj, true);
    for (int j = wlo; j <= whi; ++j)
        process(MEMN + (j - klo), (j >= jlo) && (j <= jhi));

    const float inv = 1.0f / l;
    union { uint4 u; f16x2 h2[4]; } ou;
    #pragma unroll
    for (int j = 0; j < 4; ++j) {
        ou.h2[j][0] = (_Float16)(o[2*j]   * inv);
        ou.h2[j][1] = (_Float16)(o[2*j+1] * inv);
    }
    *(uint4*)(ctx + ((size_t)b * SEQ + (iq - MEMN)) * DIM
              + (size_t)h * HEAD_DIM + sub * 8) = ou.u;
}

// ---------------------------------------------------------------------------
extern "C" void kernel_launch(void* const* d_in, const int* in_sizes, int n_in,
                              void* d_out, int out_size, void* d_ws, size_t ws_size,
                              hipStream_t stream) {
    const float* q    = (const float*)d_in[0];
    const float* k    = (const float*)d_in[1];
    const float* v    = (const float*)d_in[2];
    const float* memp = (const float*)d_in[3];
    const float* Wq   = (const float*)d_in[4];
    const float* bq   = (const float*)d_in[5];
    const float* Wk   = (const float*)d_in[6];
    const float* bk   = (const float*)d_in[7];
    const float* Wv   = (const float*)d_in[8];
    const float* bv   = (const float*)d_in[9];
    const float* Wo   = (const float*)d_in[10];
    const float* bo   = (const float*)d_in[11];
    float* out = (float*)d_out;

    const size_t NX = (size_t)MROWS * DIM;        // 2,113,536 halves
    const size_t NW = (size_t)DIM * DIM;          // 262,144 halves
    const size_t NC = (size_t)OROWS * DIM;        // 2,097,152 halves

    ushort* p   = (ushort*)d_ws;
    ushort* Xq  = p;            p += NX;
    ushort* Xk  = p;            p += NX;
    ushort* Xv  = p;            p += NX;
    ushort* Qc  = p;            p += NX;
    ushort* Kc  = p;            p += NX;
    ushort* Vc  = p;            p += NX;
    ushort* Wtq = p;            p += NW;
    ushort* Wtk = p;            p += NW;
    ushort* Wtv = p;            p += NW;
    ushort* Wto = p;            p += NW;
    ushort* Cc  = p;            p += NC;          // total ~31.7 MB

    dim3 gx((MROWS * DIM / 8 + 255) / 256, 1, 3);
    cvt_x<<<gx, 256, 0, stream>>>(q, k, v, memp, Xq, Xk, Xv);

    dim3 gw(8, 8, 4);
    cvt_wt<<<gw, 256, 0, stream>>>(Wq, Wk, Wv, Wo, Wtq, Wtk, Wtv, Wto);

    dim3 g1((MROWS + 127) / 128, 4, 3);           // 33 x 4 x 3
    gemm_qkv<<<g1, 256, 0, stream>>>(Xq, Xk, Xv, Wtq, Wtk, Wtv,
                                     bq, bk, bv, Qc, Kc, Vc);

    dim3 g2(SEQ / QBLK, NUM_HEADS, BATCH);
    attn_tiled<<<g2, 256, 0, stream>>>(Qc, Kc, Vc, Cc);

    dim3 g3(OROWS / 128, 4, 1);
    gemm_out<<<g3, 256, 0, stream>>>(Cc, Wto, bo, out);
}

// Round 8
// 86.456 us; speedup vs baseline: 10.0586x; 1.9269x over previous
//
#include <hip/hip_runtime.h>
#include <hip/hip_bf16.h>
#include <hip/hip_fp16.h>

#define DIM 512
#define NUM_HEADS 16
#define HEAD_DIM 32
#define WHALF 128
#define MEMN 16
#define SEQ 2048
#define BATCH 2
#define T_TOT (SEQ + MEMN)                 // 2064
#define MROWS (BATCH * T_TOT)              // 4128
#define OROWS (BATCH * SEQ)                // 4096
#define QT 64                              // queries per attn block
#define MAXU 352                           // padded union-window size (11*32)
#define KSTR 40                            // sK row stride (halves)
#define VSTR 360                           // sVt row stride (halves)

typedef _Float16 f16x8 __attribute__((ext_vector_type(8)));
typedef _Float16 f16x2 __attribute__((ext_vector_type(2)));
typedef __fp16   f16raw2 __attribute__((ext_vector_type(2)));   // cvt_pkrtz return type
typedef float    f32x4 __attribute__((ext_vector_type(4)));

// ---------------------------------------------------------------------------
// Prep 1: build fp16 X matrices [MROWS x 512] for q,k,v (mem rows prepended)
// ---------------------------------------------------------------------------
__global__ __launch_bounds__(256) void cvt_x(
    const float* __restrict__ q, const float* __restrict__ k,
    const float* __restrict__ v, const float* __restrict__ memp,
    ushort* __restrict__ Xq, ushort* __restrict__ Xk, ushort* __restrict__ Xv)
{
    const int which = blockIdx.z;
    const float* X = which == 0 ? q : (which == 1 ? k : v);
    ushort*     Xc = which == 0 ? Xq : (which == 1 ? Xk : Xv);

    const int gid  = blockIdx.x * 256 + threadIdx.x;
    const int base = gid * 8;
    if (base >= MROWS * DIM) return;
    const int row = base >> 9;
    const int c   = base & 511;
    const int b   = row / T_TOT;
    const int t   = row - b * T_TOT;
    const float* src = (t < MEMN)
        ? (memp + (size_t)t * DIM + c)
        : (X + ((size_t)b * SEQ + (t - MEMN)) * DIM + c);
    const float4 a0 = *(const float4*)src;
    const float4 a1 = *(const float4*)(src + 4);
    union { ushort us[8]; uint4 u4; } o;
    _Float16 h;
    h = (_Float16)a0.x; o.us[0] = *(ushort*)&h;
    h = (_Float16)a0.y; o.us[1] = *(ushort*)&h;
    h = (_Float16)a0.z; o.us[2] = *(ushort*)&h;
    h = (_Float16)a0.w; o.us[3] = *(ushort*)&h;
    h = (_Float16)a1.x; o.us[4] = *(ushort*)&h;
    h = (_Float16)a1.y; o.us[5] = *(ushort*)&h;
    h = (_Float16)a1.z; o.us[6] = *(ushort*)&h;
    h = (_Float16)a1.w; o.us[7] = *(ushort*)&h;
    *(uint4*)(Xc + (size_t)row * DIM + c) = o.u4;
}

// ---------------------------------------------------------------------------
// Prep 2: Wt[n][k] = (fp16) W[k][n]  for the 4 weight matrices
// ---------------------------------------------------------------------------
__global__ __launch_bounds__(256) void cvt_wt(
    const float* __restrict__ Wq, const float* __restrict__ Wk,
    const float* __restrict__ Wv, const float* __restrict__ Wo,
    ushort* __restrict__ Wtq, ushort* __restrict__ Wtk,
    ushort* __restrict__ Wtv, ushort* __restrict__ Wto)
{
    const int w = blockIdx.z;
    const float* W  = w == 0 ? Wq  : (w == 1 ? Wk  : (w == 2 ? Wv  : Wo));
    ushort*     Wt  = w == 0 ? Wtq : (w == 1 ? Wtk : (w == 2 ? Wtv : Wto));

    __shared__ float sT[64][65];
    const int n0 = blockIdx.x * 64;
    const int k0 = blockIdx.y * 64;

    for (int e = threadIdx.x; e < 1024; e += 256) {
        const int r  = e >> 4;
        const int c4 = e & 15;
        const float4 f = *(const float4*)(W + (size_t)(k0 + r) * DIM + n0 + c4 * 4);
        sT[r][c4 * 4 + 0] = f.x;
        sT[r][c4 * 4 + 1] = f.y;
        sT[r][c4 * 4 + 2] = f.z;
        sT[r][c4 * 4 + 3] = f.w;
    }
    __syncthreads();
    for (int u = threadIdx.x; u < 512; u += 256) {
        const int n  = u >> 3;
        const int kg = u & 7;
        union { ushort us[8]; uint4 u4; } o;
        #pragma unroll
        for (int j = 0; j < 8; ++j) {
            _Float16 h = (_Float16)sT[kg * 8 + j][n];
            o.us[j] = *(ushort*)&h;
        }
        *(uint4*)(Wt + (size_t)(n0 + n) * DIM + k0 + kg * 8) = o.u4;
    }
}

// ---------------------------------------------------------------------------
// fp16 MFMA GEMM: C[M][512] = A[M][512] @ Wt^T + bias   (Wt is [512 n][512 k])
// ---------------------------------------------------------------------------
template<bool OUT_HALF>
__device__ __forceinline__ void gemm_body(
    const ushort* __restrict__ A, const ushort* __restrict__ Bt,
    const float* __restrict__ bias, void* __restrict__ C, int M)
{
    __shared__ _Float16 sA[128][72];
    __shared__ _Float16 sB[128][72];

    const int tid  = threadIdx.x;
    const int row0 = blockIdx.x * 128;
    const int col0 = blockIdx.y * 128;
    const int wave = tid >> 6, lane = tid & 63;
    const int wr = wave >> 1, wc = wave & 1;
    const int fr = lane & 15, fq = lane >> 4;

    f32x4 acc[4][4];
    #pragma unroll
    for (int n = 0; n < 4; ++n) {
        const float bb = bias[col0 + wc * 64 + n * 16 + fr];
        #pragma unroll
        for (int m = 0; m < 4; ++m) acc[m][n] = (f32x4){bb, bb, bb, bb};
    }

    for (int k0 = 0; k0 < 512; k0 += 64) {
        __syncthreads();
        #pragma unroll
        for (int it = 0; it < 8; ++it) {
            const int u  = tid + it * 256;
            const int r  = (u >> 3) & 127;
            const int cc = u & 7;
            if (u < 1024) {
                int gr = row0 + r; if (gr >= M) gr = M - 1;
                *(uint4*)&sA[r][cc * 8] =
                    *(const uint4*)(A + (size_t)gr * 512 + k0 + cc * 8);
            } else {
                *(uint4*)&sB[r][cc * 8] =
                    *(const uint4*)(Bt + (size_t)(col0 + r) * 512 + k0 + cc * 8);
            }
        }
        __syncthreads();
        #pragma unroll
        for (int kk = 0; kk < 2; ++kk) {
            f16x8 a[4], b[4];
            #pragma unroll
            for (int m = 0; m < 4; ++m)
                a[m] = *(const f16x8*)&sA[wr * 64 + m * 16 + fr][kk * 32 + fq * 8];
            #pragma unroll
            for (int n = 0; n < 4; ++n)
                b[n] = *(const f16x8*)&sB[wc * 64 + n * 16 + fr][kk * 32 + fq * 8];
            #pragma unroll
            for (int m = 0; m < 4; ++m)
                #pragma unroll
                for (int n = 0; n < 4; ++n)
                    acc[m][n] = __builtin_amdgcn_mfma_f32_16x16x32_f16(
                        a[m], b[n], acc[m][n], 0, 0, 0);
        }
    }

    #pragma unroll
    for (int m = 0; m < 4; ++m)
        #pragma unroll
        for (int n = 0; n < 4; ++n)
            #pragma unroll
            for (int j = 0; j < 4; ++j) {
                const int row = row0 + wr * 64 + m * 16 + fq * 4 + j;
                const int col = col0 + wc * 64 + n * 16 + fr;
                if (row < M) {
                    if (OUT_HALF) {
                        _Float16 h = (_Float16)acc[m][n][j];
                        ((ushort*)C)[(size_t)row * 512 + col] = *(ushort*)&h;
                    } else {
                        ((float*)C)[(size_t)row * 512 + col] = acc[m][n][j];
                    }
                }
            }
}

__global__ __launch_bounds__(256) void gemm_qkv(
    const ushort* __restrict__ Xq, const ushort* __restrict__ Xk,
    const ushort* __restrict__ Xv,
    const ushort* __restrict__ Wtq, const ushort* __restrict__ Wtk,
    const ushort* __restrict__ Wtv,
    const float* __restrict__ bq, const float* __restrict__ bk,
    const float* __restrict__ bv,
    ushort* __restrict__ Qc, ushort* __restrict__ Kc, ushort* __restrict__ Vc)
{
    const int w = blockIdx.z;
    const ushort* A  = w == 0 ? Xq  : (w == 1 ? Xk  : Xv);
    const ushort* Bt = w == 0 ? Wtq : (w == 1 ? Wtk : Wtv);
    const float*  bi = w == 0 ? bq  : (w == 1 ? bk  : bv);
    ushort*       Cc = w == 0 ? Qc  : (w == 1 ? Kc  : Vc);
    gemm_body<true>(A, Bt, bi, Cc, MROWS);
}

__global__ __launch_bounds__(256) void gemm_out(
    const ushort* __restrict__ A, const ushort* __restrict__ Bt,
    const float* __restrict__ bias, float* __restrict__ C)
{
    gemm_body<false>(A, Bt, bias, C, OROWS);
}

// ---------------------------------------------------------------------------
// MFMA flash attention. Block = 4 waves x 16 queries (QT=64 queries/block).
// Swapped QK^T (A=K, B=Q): C[key-row][query-col]; lane(fr,fq) owns query fr,
// keys fq*4+j. PV as O^T = V^T @ P^T: m/l/alpha stay lane-local per query.
// K row-major in sK (stride 40h); V transposed in sVt[d][key] (stride 360h).
// ---------------------------------------------------------------------------
__global__ __launch_bounds__(256) void attn_mfma(
    const ushort* __restrict__ Q, const ushort* __restrict__ K,
    const ushort* __restrict__ V, ushort* __restrict__ ctx)
{
    const int tid  = threadIdx.x;
    const int tile = blockIdx.x, h = blockIdx.y, b = blockIdx.z;
    const int wave = tid >> 6, lane = tid & 63;
    const int fr = lane & 15, fq = lane >> 4;
    const int fq8 = fq * 8, fq4 = fq * 4;

    const int i0  = MEMN + tile * QT;
    const int klo = max(MEMN, i0 - WHALF);
    const int khi = min(T_TOT - 1, i0 + QT - 1 + WHALF);
    const int total = MEMN + khi - klo + 1;           // <= 336

    __shared__ ushort sK[MAXU][KSTR];                  // 27.5 KiB
    __shared__ ushort sVt[HEAD_DIM][VSTR];             // 22.5 KiB

    const size_t hbase = (size_t)b * T_TOT * DIM + (size_t)h * HEAD_DIM;

    // ---- stage K rows (zero-fill tail: prevents NaN garbage) ----
    for (int idx = tid; idx < MAXU * 4; idx += 256) {
        const int u = idx >> 2, c = idx & 3;
        uint4 val = {0, 0, 0, 0};
        if (u < total) {
            const int g = (u < MEMN) ? u : klo + u - MEMN;
            val = *(const uint4*)(K + hbase + (size_t)g * DIM + c * 8);
        }
        *(uint4*)&sK[u][c * 8] = val;
    }
    // ---- stage V transposed: u32 = (key u2, u2+1) pair per d ----
    for (int idx = tid; idx < (MAXU / 2) * 4; idx += 256) {
        const int u2 = (idx >> 2) * 2, c = idx & 3;
        union { uint4 q4; ushort us[8]; } r0, r1;
        r0.q4 = (uint4){0, 0, 0, 0};
        r1.q4 = (uint4){0, 0, 0, 0};
        if (u2 < total) {
            const int g0 = (u2 < MEMN) ? u2 : klo + u2 - MEMN;
            r0.q4 = *(const uint4*)(V + hbase + (size_t)g0 * DIM + c * 8);
        }
        if (u2 + 1 < total) {
            const int g1 = (u2 + 1 < MEMN) ? u2 + 1 : klo + u2 + 1 - MEMN;
            r1.q4 = *(const uint4*)(V + hbase + (size_t)g1 * DIM + c * 8);
        }
        #pragma unroll
        for (int ii = 0; ii < 8; ++ii) {               // rotate to spread banks
            const int i = (ii + (u2 >> 1)) & 7;
            const uint w = (uint)r0.us[i] | ((uint)r1.us[i] << 16);
            *(uint*)&sVt[c * 8 + i][u2] = w;
        }
    }

    // ---- Q fragment (B operand): lane holds Q[q=fr][d=fq*8..+7] ----
    const int iq = i0 + wave * 16 + fr;                // this lane's query
    const f16x8 qf = *(const f16x8*)(Q + (size_t)(b * T_TOT + iq) * DIM
                                     + h * HEAD_DIM + fq8);

    // per-query valid union-index range [ulo, uhi] (plus u<16 mem, unmasked)
    const int ulo  = max(iq - WHALF - klo, 0) + MEMN;
    const int uhi  = min(iq + WHALF, khi) - klo + MEMN;
    const int span = uhi - ulo;
    const int iw0  = i0 + wave * 16;
    const int ulo_min = max(iw0 - WHALF - klo, 0) + MEMN;
    const int ulo_max = max(iw0 + 15 - WHALF - klo, 0) + MEMN;
    const int uhi_min = min(iw0 + WHALF, khi) - klo + MEMN;
    const int uhi_max = min(iw0 + 15 + WHALF, khi) - klo + MEMN;

    __syncthreads();

    const float scale  = 0.17677669529663687f;         // 1/sqrt(32)
    const float NEGINF = -__builtin_huge_valf();
    float mns = -1.0e30f;                              // running max * scale
    float l   = 0.f;
    f32x4 oc0 = {0, 0, 0, 0}, oc1 = {0, 0, 0, 0};      // O^T: d=fq4+j (+16)

    const int npairs = (total + 31) >> 5;

    for (int p = 0; p < npairs; ++p) {
        const int ub = p * 32;
        if (ub >= MEMN && (ub > uhi_max || ub + 31 < ulo_min)) continue;
        const bool maskA = !((ub == 0) || (ub >= ulo_max && ub + 15 <= uhi_min));
        const bool maskB = !((ub + 16 >= ulo_max) && (ub + 31 <= uhi_min));

        // ---- QK^T: two 16-key chunks ----
        const f16x8 kfA = *(const f16x8*)&sK[ub + fr][fq8];
        const f16x8 kfB = *(const f16x8*)&sK[ub + 16 + fr][fq8];
        f32x4 sA = {0, 0, 0, 0}, sB = {0, 0, 0, 0};
        sA = __builtin_amdgcn_mfma_f32_16x16x32_f16(kfA, qf, sA, 0, 0, 0);
        sB = __builtin_amdgcn_mfma_f32_16x16x32_f16(kfB, qf, sB, 0, 0, 0);
        if (maskA) {
            #pragma unroll
            for (int j = 0; j < 4; ++j) {
                const uint uu = (uint)(ub + fq4 + j - ulo);
                sA[j] = (uu <= (uint)span) ? sA[j] : NEGINF;
            }
        }
        if (maskB) {
            #pragma unroll
            for (int j = 0; j < 4; ++j) {
                const uint uu = (uint)(ub + 16 + fq4 + j - ulo);
                sB[j] = (uu <= (uint)span) ? sB[j] : NEGINF;
            }
        }

        // ---- online softmax (group = 4 fq-lanes of query fr) ----
        float mx = fmaxf(fmaxf(fmaxf(sA[0], sA[1]), fmaxf(sA[2], sA[3])),
                         fmaxf(fmaxf(sB[0], sB[1]), fmaxf(sB[2], sB[3])));
        mx = fmaxf(mx, __shfl_xor(mx, 16));
        mx = fmaxf(mx, __shfl_xor(mx, 32));
        const float mns_new = fmaxf(mns, mx * scale);
        const float alpha   = __expf(mns - mns_new);
        float pp[8];
        #pragma unroll
        for (int j = 0; j < 4; ++j) pp[j]     = __expf(fmaf(sA[j], scale, -mns_new));
        #pragma unroll
        for (int j = 0; j < 4; ++j) pp[4 + j] = __expf(fmaf(sB[j], scale, -mns_new));
        l = fmaf(l, alpha,
                 ((pp[0] + pp[1]) + (pp[2] + pp[3])) +
                 ((pp[4] + pp[5]) + (pp[6] + pp[7])));
        mns = mns_new;
        #pragma unroll
        for (int j = 0; j < 4; ++j) { oc0[j] *= alpha; oc1[j] *= alpha; }

        // ---- pack P to fp16, redistribute to B-frag layout ----
        union { f16raw2 h2; uint u; } a0, a1, b0, b1;
        a0.h2 = __builtin_amdgcn_cvt_pkrtz(pp[0], pp[1]);
        a1.h2 = __builtin_amdgcn_cvt_pkrtz(pp[2], pp[3]);
        b0.h2 = __builtin_amdgcn_cvt_pkrtz(pp[4], pp[5]);
        b1.h2 = __builtin_amdgcn_cvt_pkrtz(pp[6], pp[7]);
        const int sl0 = fr + ((fq & 1) << 5);
        const int sl1 = sl0 + 16;
        const uint xa0 = __shfl(a0.u, sl0), xa1 = __shfl(a1.u, sl0);
        const uint xa2 = __shfl(a0.u, sl1), xa3 = __shfl(a1.u, sl1);
        const uint xb0 = __shfl(b0.u, sl0), xb1 = __shfl(b1.u, sl0);
        const uint xb2 = __shfl(b0.u, sl1), xb3 = __shfl(b1.u, sl1);
        const bool lo = (fq < 2);
        union { uint u[4]; f16x8 h; } P;
        P.u[0] = lo ? xa0 : xb0;
        P.u[1] = lo ? xa1 : xb1;
        P.u[2] = lo ? xa2 : xb2;
        P.u[3] = lo ? xa3 : xb3;

        // ---- PV: O^T += V^T @ P^T ----
        const f16x8 vf0 = *(const f16x8*)&sVt[fr][ub + fq8];
        const f16x8 vf1 = *(const f16x8*)&sVt[16 + fr][ub + fq8];
        oc0 = __builtin_amdgcn_mfma_f32_16x16x32_f16(vf0, P.h, oc0, 0, 0, 0);
        oc1 = __builtin_amdgcn_mfma_f32_16x16x32_f16(vf1, P.h, oc1, 0, 0, 0);
    }

    // ---- finalize: l reduce across fq group, divide, store fp16 ----
    l += __shfl_xor(l, 16);
    l += __shfl_xor(l, 32);
    const float inv = 1.0f / l;
    union { f16raw2 h2; uint u; } w00, w01, w10, w11;
    w00.h2 = __builtin_amdgcn_cvt_pkrtz(oc0[0] * inv, oc0[1] * inv);
    w01.h2 = __builtin_amdgcn_cvt_pkrtz(oc0[2] * inv, oc0[3] * inv);
    w10.h2 = __builtin_amdgcn_cvt_pkrtz(oc1[0] * inv, oc1[1] * inv);
    w11.h2 = __builtin_amdgcn_cvt_pkrtz(oc1[2] * inv, oc1[3] * inv);
    ushort* cp = ctx + ((size_t)b * SEQ + (iq - MEMN)) * DIM
               + h * HEAD_DIM + fq4;
    *(uint2*)cp        = (uint2){w00.u, w01.u};        // d = fq*4 .. +3
    *(uint2*)(cp + 16) = (uint2){w10.u, w11.u};        // d = 16+fq*4 .. +3
}

// ---------------------------------------------------------------------------
extern "C" void kernel_launch(void* const* d_in, const int* in_sizes, int n_in,
                              void* d_out, int out_size, void* d_ws, size_t ws_size,
                              hipStream_t stream) {
    const float* q    = (const float*)d_in[0];
    const float* k    = (const float*)d_in[1];
    const float* v    = (const float*)d_in[2];
    const float* memp = (const float*)d_in[3];
    const float* Wq   = (const float*)d_in[4];
    const float* bq   = (const float*)d_in[5];
    const float* Wk   = (const float*)d_in[6];
    const float* bk   = (const float*)d_in[7];
    const float* Wv   = (const float*)d_in[8];
    const float* bv   = (const float*)d_in[9];
    const float* Wo   = (const float*)d_in[10];
    const float* bo   = (const float*)d_in[11];
    float* out = (float*)d_out;

    const size_t NX = (size_t)MROWS * DIM;
    const size_t NW = (size_t)DIM * DIM;
    const size_t NC = (size_t)OROWS * DIM;

    ushort* p   = (ushort*)d_ws;
    ushort* Xq  = p;            p += NX;
    ushort* Xk  = p;            p += NX;
    ushort* Xv  = p;            p += NX;
    ushort* Qc  = p;            p += NX;
    ushort* Kc  = p;            p += NX;
    ushort* Vc  = p;            p += NX;
    ushort* Wtq = p;            p += NW;
    ushort* Wtk = p;            p += NW;
    ushort* Wtv = p;            p += NW;
    ushort* Wto = p;            p += NW;
    ushort* Cc  = p;            p += NC;

    dim3 gx((MROWS * DIM / 8 + 255) / 256, 1, 3);
    cvt_x<<<gx, 256, 0, stream>>>(q, k, v, memp, Xq, Xk, Xv);

    dim3 gw(8, 8, 4);
    cvt_wt<<<gw, 256, 0, stream>>>(Wq, Wk, Wv, Wo, Wtq, Wtk, Wtv, Wto);

    dim3 g1((MROWS + 127) / 128, 4, 3);
    gemm_qkv<<<g1, 256, 0, stream>>>(Xq, Xk, Xv, Wtq, Wtk, Wtv,
                                     bq, bk, bv, Qc, Kc, Vc);

    dim3 g2(SEQ / QT, NUM_HEADS, BATCH);
    attn_mfma<<<g2, 256, 0, stream>>>(Qc, Kc, Vc, Cc);

    dim3 g3(OROWS / 128, 4, 1);
    gemm_out<<<g3, 256, 0, stream>>>(Cc, Wto, bo, out);
}